// Round 11
// baseline (1653.359 us; speedup 1.0000x reference)
//
#include <hip/hip_runtime.h>
#include <math.h>

#define NN 50000
#define EE 800000
#define HID 128
#define HSZ (1u<<21)
#define CC_ROUNDS 8
#define GN 196            // ceil(NN/256)
#define WH 512            // wsum LDS hash slots
#define CH 128            // edgeagg chunk (positions per 32-lane group)
#define PF 8              // edgeagg prefetch depth (MUST match unroll factor)

// ---------------- device helpers ----------------

static __device__ __forceinline__ float sigmoid_ref(float t) {
  if (t >= 0.f) { float e = expf(-t); return 1.f / (1.f + e); }
  float e = expf(t); return e / (1.f + e);
}

static __device__ __forceinline__ int edge_count(const int* cntp, int cnst) {
  return cntp ? *cntp : cnst;
}

// ---------------- build kernels ----------------

__global__ void k_split_edges(const int* __restrict__ ei, int* __restrict__ s, int* __restrict__ d) {
  int T = gridDim.x*blockDim.x;
  for (int e = blockIdx.x*blockDim.x+threadIdx.x; e < EE; e += T) {
    s[e] = ei[2*e]; d[e] = ei[2*e+1];
  }
}

__global__ void k_degree(const int* __restrict__ eB, const int* cntp, int cnst, int* __restrict__ deg) {
  int n = edge_count(cntp, cnst);
  int T = gridDim.x*blockDim.x;
  for (int e = blockIdx.x*blockDim.x+threadIdx.x; e < n; e += T)
    atomicAdd(&deg[eB[e]], 1);
}

__global__ void k_scan1(const int* __restrict__ deg, int* __restrict__ rp, int* __restrict__ bsum) {
  __shared__ int sh[256];
  int tid = threadIdx.x; int i = blockIdx.x*256 + tid;
  int v = (i < NN) ? deg[i] : 0;
  sh[tid] = v; __syncthreads();
  for (int off = 1; off < 256; off <<= 1) {
    int t = (tid >= off) ? sh[tid-off] : 0;
    __syncthreads(); sh[tid] += t; __syncthreads();
  }
  if (i < NN) rp[i] = sh[tid] - v;
  if (tid == 255) bsum[blockIdx.x] = sh[255];
}

__global__ void k_scan2(int* __restrict__ bsum, int* __restrict__ rp, int nb) {
  __shared__ int sh[256];
  int tid = threadIdx.x;
  int v = (tid < nb) ? bsum[tid] : 0;
  sh[tid] = v; __syncthreads();
  for (int off = 1; off < 256; off <<= 1) {
    int t = (tid >= off) ? sh[tid-off] : 0;
    __syncthreads(); sh[tid] += t; __syncthreads();
  }
  if (tid < nb) bsum[tid] = sh[tid] - v;
  if (tid == 255) rp[NN] = sh[255];
}

__global__ void k_scan3(int* __restrict__ rp, const int* __restrict__ bsum, int* __restrict__ cursor,
                        const int* __restrict__ deg, float* __restrict__ dinv) {
  int i = blockIdx.x*256 + threadIdx.x;
  if (i < NN) {
    int r = rp[i] + bsum[blockIdx.x];
    rp[i] = r; cursor[i] = r;
    if (dinv) dinv[i] = (float)(1.0 / sqrt((double)(deg[i] + 2)));
  }
}

__global__ void k_csrfill(const int* __restrict__ eA, const int* __restrict__ eB,
                          const int* cntp, int cnst,
                          int* __restrict__ cursor, int* __restrict__ csr, int* __restrict__ dstE) {
  int n = edge_count(cntp, cnst);
  int T = gridDim.x*blockDim.x;
  for (int e = blockIdx.x*blockDim.x+threadIdx.x; e < n; e += T) {
    int d = eB[e];
    int p = atomicAdd(&cursor[d], 1);
    csr[p] = eA[e];
    dstE[p] = d;
  }
}

// ---------------- dense kernels ----------------

// xs[N,128]  = (concat(f(A0), g(A1 gathered)) @ W) * dinv[row]
//   f = optional relu + optional rowscale (ssum/scnt), g = optional relu
// outi[N,128] = 2*dinv[row]*xs + bias     (conv self-term, pre-aggregation)
__global__ __launch_bounds__(256) void k_matmul(
    const float* __restrict__ A0, const int* __restrict__ idx0, int reluA0,
    const float* __restrict__ rsA, const float* __restrict__ rcA,
    const float* __restrict__ A1, const int* __restrict__ idx1, int reluA1,
    int K, const float* __restrict__ W, const float* __restrict__ dinv,
    const float* __restrict__ bias, float* __restrict__ xs, float* __restrict__ outi)
{
  __shared__ __align__(16) float As[64][68];
  __shared__ __align__(16) float Bs[64][HID];
  const int tid  = threadIdx.x;
  const int row0 = blockIdx.x * 64;
  const int colg = (tid & 31) * 4;
  const int rowg = (tid >> 5) * 8;
  float acc[8][4];
  #pragma unroll
  for (int i = 0; i < 8; ++i) { acc[i][0]=0.f; acc[i][1]=0.f; acc[i][2]=0.f; acc[i][3]=0.f; }

  for (int kc = 0; kc < K; kc += 64) {
    const bool first = (kc < 128);
    const float* Asrc = first ? A0 : A1;
    const int*   aidx = first ? idx0 : idx1;
    const int    relu = first ? reluA0 : reluA1;
    const int klocal  = first ? kc : (kc - 128);
    #pragma unroll
    for (int t = tid; t < 64*16; t += 256) {
      int r  = t >> 4;
      int k4 = (t & 15) << 2;
      int grow = row0 + r;
      if (grow >= NN) grow = NN - 1;
      int gr = aidx ? aidx[grow] : grow;
      float4 v = *(const float4*)(Asrc + (size_t)gr*HID + klocal + k4);
      if (relu) {
        v.x = fmaxf(v.x,0.f); v.y = fmaxf(v.y,0.f);
        v.z = fmaxf(v.z,0.f); v.w = fmaxf(v.w,0.f);
      }
      if (first && rsA) {
        float c = rcA[gr];
        float w = (c > 0.f) ? rsA[gr]/c : 1.f;
        v.x *= w; v.y *= w; v.z *= w; v.w *= w;
      }
      As[k4+0][r] = v.x; As[k4+1][r] = v.y; As[k4+2][r] = v.z; As[k4+3][r] = v.w;
    }
    #pragma unroll
    for (int t = tid; t < 64*32; t += 256) {
      int kk = t >> 5;
      int c4 = (t & 31) << 2;
      *(float4*)&Bs[kk][c4] = *(const float4*)(W + (size_t)(kc+kk)*HID + c4);
    }
    __syncthreads();
    #pragma unroll 8
    for (int k = 0; k < 64; ++k) {
      float4 a0 = *(const float4*)&As[k][rowg];
      float4 a1 = *(const float4*)&As[k][rowg+4];
      float4 b  = *(const float4*)&Bs[k][colg];
      float ar[8] = {a0.x,a0.y,a0.z,a0.w,a1.x,a1.y,a1.z,a1.w};
      #pragma unroll
      for (int i = 0; i < 8; ++i) {
        acc[i][0] += ar[i]*b.x; acc[i][1] += ar[i]*b.y;
        acc[i][2] += ar[i]*b.z; acc[i][3] += ar[i]*b.w;
      }
    }
    __syncthreads();
  }
  float4 bb = *(const float4*)(bias + colg);
  #pragma unroll
  for (int i = 0; i < 8; ++i) {
    int r = row0 + rowg + i;
    if (r < NN) {
      float dv = dinv[r];
      float4 xv = make_float4(acc[i][0]*dv, acc[i][1]*dv, acc[i][2]*dv, acc[i][3]*dv);
      *(float4*)(xs + (size_t)r*HID + colg) = xv;
      float c2 = 2.f*dv;
      *(float4*)(outi + (size_t)r*HID + colg) =
        make_float4(xv.x*c2+bb.x, xv.y*c2+bb.y, xv.z*c2+bb.z, xv.w*c2+bb.w);
    }
  }
}

// edge-parallel aggregation: LDS-staged chunk indices + PF-deep register
// prefetch. Ring indices are compile-time constants under `#pragma unroll PF`
// (i & (PF-1)) -> stays in VGPRs (R8 regression lesson). Atomics only for
// first/last run of each chunk (interior runs are group-exclusive).
__global__ __launch_bounds__(256) void k_edgeagg(
    const float* __restrict__ xs, const int* __restrict__ csr, const int* __restrict__ dstE,
    const float* __restrict__ dinv, float* __restrict__ out,
    const int* cntp, int cnst)
{
  __shared__ int sh_s[8][CH];
  __shared__ int sh_d[8][CH];
  int n = edge_count(cntp, cnst);
  const int lane = threadIdx.x & 31;
  const int gsub = threadIdx.x >> 5;              // group within block (0..7)
  const int grp  = blockIdx.x*8 + gsub;
  const int p0   = grp * CH;
  if (p0 >= n) return;
  const int cnt = min(CH, n - p0);

  for (int j = lane; j < cnt; j += 32) {
    sh_s[gsub][j] = csr[p0 + j];
    sh_d[gsub][j] = dstE[p0 + j];
  }

  float4 pf[PF];
  #pragma unroll
  for (int j = 0; j < PF; ++j) {
    if (j < cnt) {
      int s = sh_s[gsub][j];
      pf[j] = *(const float4*)(xs + (size_t)s*HID + lane*4);
    }
  }

  int cur = sh_d[gsub][0];
  float4 acc = make_float4(0.f,0.f,0.f,0.f);
  int flushes = 0;

  #pragma unroll 8
  for (int i = 0; i < cnt; ++i) {
    float4 xv = pf[i & (PF-1)];
    int jn = i + PF;
    if (jn < cnt) {
      int sn = sh_s[gsub][jn];
      pf[i & (PF-1)] = *(const float4*)(xs + (size_t)sn*HID + lane*4);
    }
    int d = sh_d[gsub][i];
    if (d != cur) {
      float dv = dinv[cur];
      float* o = out + (size_t)cur*HID + lane*4;
      if (flushes == 0) {         // first run may extend into previous chunk
        atomicAdd(o+0, acc.x*dv); atomicAdd(o+1, acc.y*dv);
        atomicAdd(o+2, acc.z*dv); atomicAdd(o+3, acc.w*dv);
      } else {                    // interior run: exclusive to this group
        float4 ov = *(float4*)o;
        ov.x += acc.x*dv; ov.y += acc.y*dv; ov.z += acc.z*dv; ov.w += acc.w*dv;
        *(float4*)o = ov;
      }
      ++flushes;
      acc = make_float4(0.f,0.f,0.f,0.f);
      cur = d;
    }
    acc.x += xv.x; acc.y += xv.y; acc.z += xv.z; acc.w += xv.w;
  }
  float dv = dinv[cur];           // last run may extend into next chunk
  float* o = out + (size_t)cur*HID + lane*4;
  atomicAdd(o+0, acc.x*dv); atomicAdd(o+1, acc.y*dv);
  atomicAdd(o+2, acc.z*dv); atomicAdd(o+3, acc.w*dv);
}

// ---------------- pooling kernels ----------------

// inputs are pre-relu h; relu applied on load
__global__ __launch_bounds__(256) void k_node_ab(
    const float* __restrict__ h, const float* __restrict__ Wp,
    float* __restrict__ an, float* __restrict__ bn)
{
  int l = threadIdx.x & 63;
  int sub = threadIdx.x >> 6;
  float w0 = Wp[l], w1 = Wp[64+l], w2 = Wp[128+l], w3 = Wp[192+l];
  for (int g = blockIdx.x; g*4 < NN; g += gridDim.x) {
    int v = g*4 + sub;
    if (v >= NN) continue;
    float h0 = fmaxf(h[(size_t)v*HID + l], 0.f);
    float h1 = fmaxf(h[(size_t)v*HID + 64 + l], 0.f);
    float a = h0*w0 + h1*w1;
    float b = h0*w2 + h1*w3;
    #pragma unroll
    for (int off = 32; off; off >>= 1) { a += __shfl_down(a, off); b += __shfl_down(b, off); }
    if (l == 0) { an[v] = a; bn[v] = b; }
  }
}

__global__ void k_labinit(int* __restrict__ lab, int* __restrict__ flags,
                          int* __restrict__ selcnt, int* ecnt_next,
                          float* __restrict__ ssum2) {
  int i = blockIdx.x*256 + threadIdx.x;
  int T = gridDim.x*256;
  if (i < NN) lab[i] = i;
  for (int j = i; j < 2*NN; j += T) ssum2[j] = 0.f;
  if (i < 32) flags[i] = 0;
  if (i == 32) *selcnt = 0;
  if (i == 33 && ecnt_next) *ecnt_next = 0;
}

__global__ __launch_bounds__(256) void k_score_sel(
    const int* __restrict__ eA, const int* __restrict__ eB, const int* cntp, int cnst,
    const float* __restrict__ an, const float* __restrict__ bn, const float* __restrict__ bp,
    int* __restrict__ selA, int* __restrict__ selB, float* __restrict__ selS,
    int* __restrict__ selcnt)
{
  int n = edge_count(cntp, cnst);
  int T = gridDim.x*blockDim.x;
  int lane = threadIdx.x & 63;
  for (int e = blockIdx.x*blockDim.x+threadIdx.x; e < n; e += T) {
    int a = eA[e], b = eB[e];
    bool pred = false; float s = 0.f;
    if (a != b) {
      s = sigmoid_ref(an[a] + bn[b] + bp[0]);
      pred = s > 0.5f;
    }
    unsigned long long mask = __ballot(pred);
    if (mask) {
      int leader = __ffsll((long long)mask) - 1;
      int total  = __popcll(mask);
      int base = 0;
      if (lane == leader) base = atomicAdd(selcnt, total);
      base = __shfl(base, leader);
      if (pred) {
        int off = __popcll(mask & ((1ull << lane) - 1));
        selA[base+off] = a; selB[base+off] = b; selS[base+off] = s;
      }
    }
  }
}

// fused CC round: 2-hop min-label hook over compacted edges, then 3-level
// pointer jump over nodes. No internal sync needed: labels are monotone
// (atomicMin / improving plain stores), launch boundaries are quiescent, and
// the gated early-exit (no change in a full round => converged) is preserved.
__global__ __launch_bounds__(256) void k_ccround(
    const int* __restrict__ selA, const int* __restrict__ selB, const int* __restrict__ selcnt,
    int* __restrict__ lab, const int* flagPrev, int* __restrict__ flagCur)
{
  if (flagPrev && *flagPrev == 0) return;
  int n = *selcnt;
  int T = gridDim.x*blockDim.x;
  int t0 = blockIdx.x*blockDim.x+threadIdx.x;
  bool changed = false;
  for (int i = t0; i < n; i += T) {
    int a = selA[i], b = selB[i];
    int la = lab[a], lb = lab[b];
    if (la == lb) continue;
    int pla = lab[la], plb = lab[lb];
    int m = min(pla, plb);
    if (la > m && lab[a] > m) atomicMin(&lab[a], m);
    if (lb > m && lab[b] > m) atomicMin(&lab[b], m);
    if (pla > m) atomicMin(&lab[la], m);
    if (plb > m) atomicMin(&lab[lb], m);
    changed = true;
  }
  for (int v = t0; v < NN; v += T) {
    int l0 = lab[v];
    int l = lab[l0]; l = lab[l]; l = lab[l];
    if (l < l0) { lab[v] = l; changed = true; }
  }
  unsigned long long m2 = __ballot(changed);
  if (m2 && (threadIdx.x & 63) == __ffsll((long long)m2) - 1) *flagCur = 1;
}

// per-cluster (ssum, scnt); LDS hash accumulator, probe-bounded w/ global fallback
__global__ __launch_bounds__(256) void k_wsum(
    const int* __restrict__ selA, const float* __restrict__ selS,
    const int* __restrict__ selcnt, const int* __restrict__ cl,
    float* __restrict__ ssum, float* __restrict__ scnt)
{
  __shared__ int key[WH];
  __shared__ float vs[WH];
  __shared__ float vc[WH];
  int n = *selcnt;
  for (int i = threadIdx.x; i < WH; i += 256) { key[i] = -1; vs[i] = 0.f; vc[i] = 0.f; }
  __syncthreads();
  int T = gridDim.x*blockDim.x;
  for (int e = blockIdx.x*blockDim.x+threadIdx.x; e < n; e += T) {
    int c = cl[selA[e]];
    float s = selS[e];
    unsigned h = ((unsigned)c * 2654435761u) & (WH-1);
    bool done = false;
    for (int probe = 0; probe < 32; ++probe) {
      int k = key[h];
      if (k == c) { atomicAdd(&vs[h], s); atomicAdd(&vc[h], 1.f); done = true; break; }
      if (k == -1) {
        int old = atomicCAS(&key[h], -1, c);
        if (old == -1 || old == c) { atomicAdd(&vs[h], s); atomicAdd(&vc[h], 1.f); done = true; break; }
      }
      h = (h+1) & (WH-1);
    }
    if (!done) { atomicAdd(&ssum[c], s); atomicAdd(&scnt[c], 1.f); }
  }
  __syncthreads();
  for (int i = threadIdx.x; i < WH; i += 256) {
    if (key[i] >= 0) { atomicAdd(&ssum[key[i]], vs[i]); atomicAdd(&scnt[key[i]], vc[i]); }
  }
}

// p[cluster[v]] += relu(h[v]), run-length flushed per feature lane; 64-node segments
__global__ __launch_bounds__(128) void k_poolsum(const float* __restrict__ h,
                                                 const int* __restrict__ cl, float* __restrict__ p) {
  int f = threadIdx.x;
  int base = blockIdx.x * 64;
  int cur = -1; float acc = 0.f;
  for (int j = 0; j < 64; ++j) {
    int v = base + j;
    if (v >= NN) break;
    int c = cl[v];
    float x = fmaxf(h[(size_t)v*HID + f], 0.f);
    if (c == cur) acc += x;
    else {
      if (cur >= 0) atomicAdd(&p[(size_t)cur*HID + f], acc);
      cur = c; acc = x;
    }
  }
  if (cur >= 0) atomicAdd(&p[(size_t)cur*HID + f], acc);
}

__global__ __launch_bounds__(256) void k_contract(
    const int* __restrict__ eA, const int* __restrict__ eB, const int* cntp, int cnst,
    const int* __restrict__ cl, unsigned long long* __restrict__ tab,
    int* __restrict__ outA, int* __restrict__ outB, int* __restrict__ ocnt, int lev)
{
  int n = edge_count(cntp, cnst);
  int T = gridDim.x*blockDim.x;
  int lane = threadIdx.x & 63;
  for (int e = blockIdx.x*blockDim.x+threadIdx.x; e < n; e += T) {
    int s = eA[e], d = eB[e];
    bool keep = false; int a = 0, b = 0;
    if (s != d) {
      a = cl[s]; b = cl[d];
      if (a != b) {
        unsigned long long key = ((unsigned long long)lev << 34) |
                                 ((unsigned long long)a << 17) | (unsigned long long)b;
        unsigned long long hh = key * 0x9E3779B97F4A7C15ull;
        unsigned idx = (unsigned)(hh >> 40) & (HSZ - 1);
        while (true) {
          unsigned long long prev = atomicCAS(&tab[idx], ~0ull, key);
          if (prev == ~0ull) { keep = true; break; }
          if (prev == key) break;
          idx = (idx + 1) & (HSZ - 1);
        }
      }
    }
    unsigned long long mask = __ballot(keep);
    if (mask) {
      int leader = __ffsll((long long)mask) - 1;
      int total  = __popcll(mask);
      int base = 0;
      if (lane == leader) base = atomicAdd(ocnt, total);
      base = __shfl(base, leader);
      if (keep) {
        int off = __popcll(mask & ((1ull << lane) - 1));
        outA[base+off] = a; outB[base+off] = b;
      }
    }
  }
}

// ---------------- output kernels ----------------

// h1 and u1 are pre-relu -> relu on load; xin raw
__global__ __launch_bounds__(256) void k_matvec384(
    const float* __restrict__ h1, const float* __restrict__ xin,
    const float* __restrict__ u1, const int* __restrict__ cl0,
    const float* __restrict__ Wu2, float* __restrict__ zw)
{
  int l = threadIdx.x & 63;
  int sub = threadIdx.x >> 6;
  float w0 = Wu2[l],     w1 = Wu2[64+l],  w2 = Wu2[128+l];
  float w3 = Wu2[192+l], w4 = Wu2[256+l], w5 = Wu2[320+l];
  for (int g = blockIdx.x; g*4 < NN; g += gridDim.x) {
    int v = g*4 + sub;
    if (v >= NN) continue;
    int gg = cl0[v];
    float s = fmaxf(h1[(size_t)v*HID + l], 0.f)       * w0
            + fmaxf(h1[(size_t)v*HID + 64 + l], 0.f)  * w1
            + xin[(size_t)v*HID + l]                  * w2
            + xin[(size_t)v*HID + 64 + l]             * w3
            + fmaxf(u1[(size_t)gg*HID + l], 0.f)      * w4
            + fmaxf(u1[(size_t)gg*HID + 64 + l], 0.f) * w5;
    #pragma unroll
    for (int off = 32; off; off >>= 1) s += __shfl_down(s, off);
    if (l == 0) zw[v] = s;
  }
}

__global__ void k_final(const float* __restrict__ zw, const int* __restrict__ rp,
                        const int* __restrict__ csr, const float* __restrict__ dinv,
                        const float* __restrict__ bu, float* __restrict__ out) {
  int T = gridDim.x*blockDim.x;
  for (int v = blockIdx.x*blockDim.x+threadIdx.x; v < NN; v += T) {
    float acc = 0.f;
    int p0 = rp[v], p1 = rp[v+1];
    for (int p = p0; p < p1; ++p) { int s = csr[p]; acc += zw[s]*dinv[s]; }
    float dv = dinv[v];
    float t = acc*dv + 2.f*dv*dv*zw[v] + bu[0];
    out[v] = sigmoid_ref(t);
  }
}

// ---------------- host orchestration ----------------

extern "C" void kernel_launch(void* const* d_in, const int* in_sizes, int n_in,
                              void* d_out, int out_size, void* d_ws, size_t ws_size,
                              hipStream_t stream) {
  const float* x_in = (const float*)d_in[0];
  const int*   ei   = (const int*)d_in[1];
  const float* Wd0 = (const float*)d_in[3];  const float* bd0 = (const float*)d_in[4];
  const float* Wd1 = (const float*)d_in[5];  const float* bd1 = (const float*)d_in[6];
  const float* Wd2 = (const float*)d_in[7];  const float* bd2 = (const float*)d_in[8];
  const float* Wd3 = (const float*)d_in[9];  const float* bd3 = (const float*)d_in[10];
  const float* Wp0 = (const float*)d_in[11]; const float* bp0 = (const float*)d_in[12];
  const float* Wp1 = (const float*)d_in[13]; const float* bp1 = (const float*)d_in[14];
  const float* Wp2 = (const float*)d_in[15]; const float* bp2 = (const float*)d_in[16];
  const float* Wu0 = (const float*)d_in[17]; const float* bu0 = (const float*)d_in[18];
  const float* Wu1 = (const float*)d_in[19]; const float* bu1 = (const float*)d_in[20];
  const float* Wu2 = (const float*)d_in[21]; const float* bu2 = (const float*)d_in[22];
  float* out = (float*)d_out;
  (void)in_sizes; (void)n_in; (void)out_size;

  char* wp = (char*)d_ws;
  auto alloc = [&](size_t bytes) -> void* {
    void* p = (void*)wp;
    wp += (bytes + 255) & ~(size_t)255;
    return p;
  };
  float* B[6]; for (int i = 0; i < 6; ++i) B[i] = (float*)alloc((size_t)NN*HID*4);
  int *eA[4], *eB[4];
  for (int i = 0; i < 4; ++i) { eA[i] = (int*)alloc((size_t)EE*4); eB[i] = (int*)alloc((size_t)EE*4); }
  int* cl[3];      for (int i = 0; i < 3; ++i) cl[i]    = (int*)alloc((size_t)NN*4);
  float* dinvL[4]; for (int i = 0; i < 4; ++i) dinvL[i] = (float*)alloc((size_t)NN*4);
  int* rpL[4]; int* csrL[4]; int* dstL[4];
  for (int i = 0; i < 4; ++i) {
    rpL[i]  = (int*)alloc((size_t)(NN+1)*4);
    csrL[i] = (int*)alloc((size_t)EE*4);
    dstL[i] = (int*)alloc((size_t)EE*4);
  }
  int*   selA = (int*)alloc((size_t)EE*4);
  int*   selB = (int*)alloc((size_t)EE*4);
  float* selS = (float*)alloc((size_t)EE*4);
  int* deg    = (int*)alloc((size_t)NN*4);
  int* cursor = (int*)alloc((size_t)NN*4);
  int* bsum   = (int*)alloc(256*4);
  float* an   = (float*)alloc((size_t)NN*4);
  float* bn   = (float*)alloc((size_t)NN*4);
  float* ssum = (float*)alloc((size_t)2*NN*4);
  float* scnt = ssum + NN;
  float* zw   = (float*)alloc((size_t)NN*4);
  int* selcnt = (int*)alloc(256);
  int* ecnt   = (int*)alloc(256);
  int* flags  = (int*)alloc(256);
  unsigned long long* tab = (unsigned long long*)alloc((size_t)HSZ*8);
  if ((size_t)(wp - (char*)d_ws) > ws_size) return;

  k_split_edges<<<1024,256,0,stream>>>(ei, eA[0], eB[0]);
  hipMemsetAsync(tab, 0xFF, (size_t)HSZ*8, stream);

  auto cntp = [&](int lev) -> const int* { return lev ? (ecnt + lev) : nullptr; };

  auto build_level = [&](int lev) {
    hipMemsetAsync(deg, 0, (size_t)NN*4, stream);
    k_degree<<<512,256,0,stream>>>(eB[lev], cntp(lev), EE, deg);
    k_scan1<<<GN,256,0,stream>>>(deg, rpL[lev], bsum);
    k_scan2<<<1,256,0,stream>>>(bsum, rpL[lev], GN);
    k_scan3<<<GN,256,0,stream>>>(rpL[lev], bsum, cursor, deg, dinvL[lev]);
    k_csrfill<<<512,256,0,stream>>>(eA[lev], eB[lev], cntp(lev), EE, cursor, csrL[lev], dstL[lev]);
  };

  const int GAGG = (EE + 8*CH - 1) / (8*CH);
  auto do_conv = [&](const float* A0, int reluA0, const float* rs, const float* rc,
                     const float* A1, const int* i1, int reluA1, int K,
                     const float* W, const float* bias, int lev, float* xs, float* outp) {
    k_matmul<<<(NN+63)/64,256,0,stream>>>(A0, nullptr, reluA0, rs, rc,
                                          A1, i1, reluA1, K, W, dinvL[lev], bias, xs, outp);
    k_edgeagg<<<GAGG,256,0,stream>>>(xs, csrL[lev], dstL[lev], dinvL[lev], outp, cntp(lev), EE);
  };

  auto do_pool = [&](const float* h, int lev, int ci, float* p, const float* Wp, const float* bp) {
    k_node_ab<<<512,256,0,stream>>>(h, Wp, an, bn);
    k_labinit<<<GN,256,0,stream>>>(cl[ci], flags, selcnt, ecnt + lev + 1, ssum);
    k_score_sel<<<512,256,0,stream>>>(eA[lev], eB[lev], cntp(lev), EE, an, bn, bp,
                                      selA, selB, selS, selcnt);
    for (int r = 0; r < CC_ROUNDS; ++r) {
      const int* fp = r ? (flags + r - 1) : nullptr;
      k_ccround<<<512,256,0,stream>>>(selA, selB, selcnt, cl[ci], fp, flags + r);
    }
    k_wsum<<<64,256,0,stream>>>(selA, selS, selcnt, cl[ci], ssum, scnt);
    hipMemsetAsync(p, 0, (size_t)NN*HID*4, stream);
    k_poolsum<<<(NN+63)/64,128,0,stream>>>(h, cl[ci], p);   // raw pooled sums; w applied at next matmul
    k_contract<<<512,256,0,stream>>>(eA[lev], eB[lev], cntp(lev), EE, cl[ci], tab,
                                     eA[lev+1], eB[lev+1], ecnt + lev + 1, lev);
  };

  // ---- down path (h buffers hold PRE-relu values) ----
  build_level(0);
  do_conv(x_in, 0, nullptr, nullptr, nullptr, nullptr, 0, 128, Wd0, bd0, 0, B[5], B[0]); // h1=B0
  do_pool(B[0], 0, 0, B[3], Wp0, bp0);                                                   // p1=B3 (raw)
  build_level(1);
  do_conv(B[3], 0, ssum, scnt, nullptr, nullptr, 0, 128, Wd1, bd1, 1, B[5], B[1]);       // h2=B1
  do_pool(B[1], 1, 1, B[3], Wp1, bp1);                                                   // p2=B3
  build_level(2);
  do_conv(B[3], 0, ssum, scnt, nullptr, nullptr, 0, 128, Wd2, bd2, 2, B[5], B[2]);       // h3=B2
  do_pool(B[2], 2, 2, B[3], Wp2, bp2);                                                   // p3=B3
  build_level(3);
  do_conv(B[3], 0, ssum, scnt, nullptr, nullptr, 0, 128, Wd3, bd3, 3, B[5], B[4]);       // h4=B4 (no relu ever)
  // ---- up path (concat folded; A-relu on load; A1 row-gathered) ----
  do_conv(B[2], 1, nullptr, nullptr, B[4], cl[2], 0, 256, Wu0, bu0, 2, B[5], B[3]);      // u0=B3
  do_conv(B[1], 1, nullptr, nullptr, B[3], cl[1], 1, 256, Wu1, bu1, 1, B[5], B[4]);      // u1=B4
  k_matvec384<<<512,256,0,stream>>>(B[0], x_in, B[4], cl[0], Wu2, zw);
  k_final<<<512,256,0,stream>>>(zw, rpL[0], csrL[0], dinvL[0], bu2, out);
}

// Round 12
// 1604.945 us; speedup vs baseline: 1.0302x; 1.0302x over previous
//
#include <hip/hip_runtime.h>
#include <math.h>

#define NN 50000
#define EE 800000
#define HID 128
#define HSZ (1u<<21)
#define CC_ROUNDS 8
#define GN 196            // ceil(NN/256)
#define WH 512            // wsum LDS hash slots
#define CH 128            // edgeagg chunk (positions per 32-lane group)
#define PF 4              // edgeagg prefetch depth (4 measured optimal; 8 thrashes L2 — R10)

// ---------------- device helpers ----------------

static __device__ __forceinline__ float sigmoid_ref(float t) {
  if (t >= 0.f) { float e = expf(-t); return 1.f / (1.f + e); }
  float e = expf(t); return e / (1.f + e);
}

static __device__ __forceinline__ int edge_count(const int* cntp, int cnst) {
  return cntp ? *cntp : cnst;
}

// ---------------- build kernels ----------------

__global__ void k_split_edges(const int* __restrict__ ei, int* __restrict__ s, int* __restrict__ d) {
  int T = gridDim.x*blockDim.x;
  for (int e = blockIdx.x*blockDim.x+threadIdx.x; e < EE; e += T) {
    s[e] = ei[2*e]; d[e] = ei[2*e+1];
  }
}

__global__ void k_degree(const int* __restrict__ eB, const int* cntp, int cnst, int* __restrict__ deg) {
  int n = edge_count(cntp, cnst);
  int T = gridDim.x*blockDim.x;
  for (int e = blockIdx.x*blockDim.x+threadIdx.x; e < n; e += T)
    atomicAdd(&deg[eB[e]], 1);
}

__global__ void k_scan1(const int* __restrict__ deg, int* __restrict__ rp, int* __restrict__ bsum) {
  __shared__ int sh[256];
  int tid = threadIdx.x; int i = blockIdx.x*256 + tid;
  int v = (i < NN) ? deg[i] : 0;
  sh[tid] = v; __syncthreads();
  for (int off = 1; off < 256; off <<= 1) {
    int t = (tid >= off) ? sh[tid-off] : 0;
    __syncthreads(); sh[tid] += t; __syncthreads();
  }
  if (i < NN) rp[i] = sh[tid] - v;
  if (tid == 255) bsum[blockIdx.x] = sh[255];
}

__global__ void k_scan2(int* __restrict__ bsum, int* __restrict__ rp, int nb) {
  __shared__ int sh[256];
  int tid = threadIdx.x;
  int v = (tid < nb) ? bsum[tid] : 0;
  sh[tid] = v; __syncthreads();
  for (int off = 1; off < 256; off <<= 1) {
    int t = (tid >= off) ? sh[tid-off] : 0;
    __syncthreads(); sh[tid] += t; __syncthreads();
  }
  if (tid < nb) bsum[tid] = sh[tid] - v;
  if (tid == 255) rp[NN] = sh[255];
}

__global__ void k_scan3(int* __restrict__ rp, const int* __restrict__ bsum, int* __restrict__ cursor,
                        const int* __restrict__ deg, float* __restrict__ dinv) {
  int i = blockIdx.x*256 + threadIdx.x;
  if (i < NN) {
    int r = rp[i] + bsum[blockIdx.x];
    rp[i] = r; cursor[i] = r;
    if (dinv) dinv[i] = (float)(1.0 / sqrt((double)(deg[i] + 2)));
  }
}

__global__ void k_csrfill(const int* __restrict__ eA, const int* __restrict__ eB,
                          const int* cntp, int cnst,
                          int* __restrict__ cursor, int* __restrict__ csr, int* __restrict__ dstE) {
  int n = edge_count(cntp, cnst);
  int T = gridDim.x*blockDim.x;
  for (int e = blockIdx.x*blockDim.x+threadIdx.x; e < n; e += T) {
    int d = eB[e];
    int p = atomicAdd(&cursor[d], 1);
    csr[p] = eA[e];
    dstE[p] = d;
  }
}

// ---------------- dense kernels ----------------

// xs[N,128]  = (concat(f(A0), g(A1 gathered)) @ W) * dinv[row]
//   f = optional relu + optional rowscale (ssum/scnt), g = optional relu
// outi[N,128] = 2*dinv[row]*xs + bias     (conv self-term, pre-aggregation)
__global__ __launch_bounds__(256) void k_matmul(
    const float* __restrict__ A0, const int* __restrict__ idx0, int reluA0,
    const float* __restrict__ rsA, const float* __restrict__ rcA,
    const float* __restrict__ A1, const int* __restrict__ idx1, int reluA1,
    int K, const float* __restrict__ W, const float* __restrict__ dinv,
    const float* __restrict__ bias, float* __restrict__ xs, float* __restrict__ outi)
{
  __shared__ __align__(16) float As[64][68];
  __shared__ __align__(16) float Bs[64][HID];
  const int tid  = threadIdx.x;
  const int row0 = blockIdx.x * 64;
  const int colg = (tid & 31) * 4;
  const int rowg = (tid >> 5) * 8;
  float acc[8][4];
  #pragma unroll
  for (int i = 0; i < 8; ++i) { acc[i][0]=0.f; acc[i][1]=0.f; acc[i][2]=0.f; acc[i][3]=0.f; }

  for (int kc = 0; kc < K; kc += 64) {
    const bool first = (kc < 128);
    const float* Asrc = first ? A0 : A1;
    const int*   aidx = first ? idx0 : idx1;
    const int    relu = first ? reluA0 : reluA1;
    const int klocal  = first ? kc : (kc - 128);
    #pragma unroll
    for (int t = tid; t < 64*16; t += 256) {
      int r  = t >> 4;
      int k4 = (t & 15) << 2;
      int grow = row0 + r;
      if (grow >= NN) grow = NN - 1;
      int gr = aidx ? aidx[grow] : grow;
      float4 v = *(const float4*)(Asrc + (size_t)gr*HID + klocal + k4);
      if (relu) {
        v.x = fmaxf(v.x,0.f); v.y = fmaxf(v.y,0.f);
        v.z = fmaxf(v.z,0.f); v.w = fmaxf(v.w,0.f);
      }
      if (first && rsA) {
        float c = rcA[gr];
        float w = (c > 0.f) ? rsA[gr]/c : 1.f;
        v.x *= w; v.y *= w; v.z *= w; v.w *= w;
      }
      As[k4+0][r] = v.x; As[k4+1][r] = v.y; As[k4+2][r] = v.z; As[k4+3][r] = v.w;
    }
    #pragma unroll
    for (int t = tid; t < 64*32; t += 256) {
      int kk = t >> 5;
      int c4 = (t & 31) << 2;
      *(float4*)&Bs[kk][c4] = *(const float4*)(W + (size_t)(kc+kk)*HID + c4);
    }
    __syncthreads();
    #pragma unroll 8
    for (int k = 0; k < 64; ++k) {
      float4 a0 = *(const float4*)&As[k][rowg];
      float4 a1 = *(const float4*)&As[k][rowg+4];
      float4 b  = *(const float4*)&Bs[k][colg];
      float ar[8] = {a0.x,a0.y,a0.z,a0.w,a1.x,a1.y,a1.z,a1.w};
      #pragma unroll
      for (int i = 0; i < 8; ++i) {
        acc[i][0] += ar[i]*b.x; acc[i][1] += ar[i]*b.y;
        acc[i][2] += ar[i]*b.z; acc[i][3] += ar[i]*b.w;
      }
    }
    __syncthreads();
  }
  float4 bb = *(const float4*)(bias + colg);
  #pragma unroll
  for (int i = 0; i < 8; ++i) {
    int r = row0 + rowg + i;
    if (r < NN) {
      float dv = dinv[r];
      float4 xv = make_float4(acc[i][0]*dv, acc[i][1]*dv, acc[i][2]*dv, acc[i][3]*dv);
      *(float4*)(xs + (size_t)r*HID + colg) = xv;
      float c2 = 2.f*dv;
      *(float4*)(outi + (size_t)r*HID + colg) =
        make_float4(xv.x*c2+bb.x, xv.y*c2+bb.y, xv.z*c2+bb.z, xv.w*c2+bb.w);
    }
  }
}

// edge-parallel aggregation (R9-proven): LDS-staged chunk indices + 4-deep
// register prefetch (compile-time ring indices under unroll 4 -> stays in
// VGPRs; PF=8 thrashes L2). Atomics only for first/last run of each chunk.
__global__ __launch_bounds__(256) void k_edgeagg(
    const float* __restrict__ xs, const int* __restrict__ csr, const int* __restrict__ dstE,
    const float* __restrict__ dinv, float* __restrict__ out,
    const int* cntp, int cnst)
{
  __shared__ int sh_s[8][CH];
  __shared__ int sh_d[8][CH];
  int n = edge_count(cntp, cnst);
  const int lane = threadIdx.x & 31;
  const int gsub = threadIdx.x >> 5;              // group within block (0..7)
  const int grp  = blockIdx.x*8 + gsub;
  const int p0   = grp * CH;
  if (p0 >= n) return;
  const int cnt = min(CH, n - p0);

  for (int j = lane; j < cnt; j += 32) {
    sh_s[gsub][j] = csr[p0 + j];
    sh_d[gsub][j] = dstE[p0 + j];
  }

  float4 pf[PF];
  #pragma unroll
  for (int j = 0; j < PF; ++j) {
    if (j < cnt) {
      int s = sh_s[gsub][j];
      pf[j] = *(const float4*)(xs + (size_t)s*HID + lane*4);
    }
  }

  int cur = sh_d[gsub][0];
  float4 acc = make_float4(0.f,0.f,0.f,0.f);
  int flushes = 0;

  #pragma unroll 4
  for (int i = 0; i < cnt; ++i) {
    float4 xv = pf[i & (PF-1)];
    int jn = i + PF;
    if (jn < cnt) {
      int sn = sh_s[gsub][jn];
      pf[i & (PF-1)] = *(const float4*)(xs + (size_t)sn*HID + lane*4);
    }
    int d = sh_d[gsub][i];
    if (d != cur) {
      float dv = dinv[cur];
      float* o = out + (size_t)cur*HID + lane*4;
      if (flushes == 0) {         // first run may extend into previous chunk
        atomicAdd(o+0, acc.x*dv); atomicAdd(o+1, acc.y*dv);
        atomicAdd(o+2, acc.z*dv); atomicAdd(o+3, acc.w*dv);
      } else {                    // interior run: exclusive to this group
        float4 ov = *(float4*)o;
        ov.x += acc.x*dv; ov.y += acc.y*dv; ov.z += acc.z*dv; ov.w += acc.w*dv;
        *(float4*)o = ov;
      }
      ++flushes;
      acc = make_float4(0.f,0.f,0.f,0.f);
      cur = d;
    }
    acc.x += xv.x; acc.y += xv.y; acc.z += xv.z; acc.w += xv.w;
  }
  float dv = dinv[cur];           // last run may extend into next chunk
  float* o = out + (size_t)cur*HID + lane*4;
  atomicAdd(o+0, acc.x*dv); atomicAdd(o+1, acc.y*dv);
  atomicAdd(o+2, acc.z*dv); atomicAdd(o+3, acc.w*dv);
}

// ---------------- pooling kernels ----------------

// inputs are pre-relu h; relu applied on load
__global__ __launch_bounds__(256) void k_node_ab(
    const float* __restrict__ h, const float* __restrict__ Wp,
    float* __restrict__ an, float* __restrict__ bn)
{
  int l = threadIdx.x & 63;
  int sub = threadIdx.x >> 6;
  float w0 = Wp[l], w1 = Wp[64+l], w2 = Wp[128+l], w3 = Wp[192+l];
  for (int g = blockIdx.x; g*4 < NN; g += gridDim.x) {
    int v = g*4 + sub;
    if (v >= NN) continue;
    float h0 = fmaxf(h[(size_t)v*HID + l], 0.f);
    float h1 = fmaxf(h[(size_t)v*HID + 64 + l], 0.f);
    float a = h0*w0 + h1*w1;
    float b = h0*w2 + h1*w3;
    #pragma unroll
    for (int off = 32; off; off >>= 1) { a += __shfl_down(a, off); b += __shfl_down(b, off); }
    if (l == 0) { an[v] = a; bn[v] = b; }
  }
}

__global__ void k_labinit(int* __restrict__ lab, int* __restrict__ flags,
                          int* __restrict__ selcnt, int* ecnt_next,
                          float* __restrict__ ssum2) {
  int i = blockIdx.x*256 + threadIdx.x;
  int T = gridDim.x*256;
  if (i < NN) lab[i] = i;
  for (int j = i; j < 2*NN; j += T) ssum2[j] = 0.f;
  if (i < 32) flags[i] = 0;
  if (i == 32) *selcnt = 0;
  if (i == 33 && ecnt_next) *ecnt_next = 0;
}

__global__ __launch_bounds__(256) void k_score_sel(
    const int* __restrict__ eA, const int* __restrict__ eB, const int* cntp, int cnst,
    const float* __restrict__ an, const float* __restrict__ bn, const float* __restrict__ bp,
    int* __restrict__ selA, int* __restrict__ selB, float* __restrict__ selS,
    int* __restrict__ selcnt)
{
  int n = edge_count(cntp, cnst);
  int T = gridDim.x*blockDim.x;
  int lane = threadIdx.x & 63;
  for (int e = blockIdx.x*blockDim.x+threadIdx.x; e < n; e += T) {
    int a = eA[e], b = eB[e];
    bool pred = false; float s = 0.f;
    if (a != b) {
      s = sigmoid_ref(an[a] + bn[b] + bp[0]);
      pred = s > 0.5f;
    }
    unsigned long long mask = __ballot(pred);
    if (mask) {
      int leader = __ffsll((long long)mask) - 1;
      int total  = __popcll(mask);
      int base = 0;
      if (lane == leader) base = atomicAdd(selcnt, total);
      base = __shfl(base, leader);
      if (pred) {
        int off = __popcll(mask & ((1ull << lane) - 1));
        selA[base+off] = a; selB[base+off] = b; selS[base+off] = s;
      }
    }
  }
}

// fused CC round: 2-hop min-label hook over compacted edges, then 3-level
// pointer jump over nodes (monotone; gated early-exit preserved)
__global__ __launch_bounds__(256) void k_ccround(
    const int* __restrict__ selA, const int* __restrict__ selB, const int* __restrict__ selcnt,
    int* __restrict__ lab, const int* flagPrev, int* __restrict__ flagCur)
{
  if (flagPrev && *flagPrev == 0) return;
  int n = *selcnt;
  int T = gridDim.x*blockDim.x;
  int t0 = blockIdx.x*blockDim.x+threadIdx.x;
  bool changed = false;
  for (int i = t0; i < n; i += T) {
    int a = selA[i], b = selB[i];
    int la = lab[a], lb = lab[b];
    if (la == lb) continue;
    int pla = lab[la], plb = lab[lb];
    int m = min(pla, plb);
    if (la > m && lab[a] > m) atomicMin(&lab[a], m);
    if (lb > m && lab[b] > m) atomicMin(&lab[b], m);
    if (pla > m) atomicMin(&lab[la], m);
    if (plb > m) atomicMin(&lab[lb], m);
    changed = true;
  }
  for (int v = t0; v < NN; v += T) {
    int l0 = lab[v];
    int l = lab[l0]; l = lab[l]; l = lab[l];
    if (l < l0) { lab[v] = l; changed = true; }
  }
  unsigned long long m2 = __ballot(changed);
  if (m2 && (threadIdx.x & 63) == __ffsll((long long)m2) - 1) *flagCur = 1;
}

// per-cluster (ssum, scnt); LDS hash accumulator, probe-bounded w/ global fallback
__global__ __launch_bounds__(256) void k_wsum(
    const int* __restrict__ selA, const float* __restrict__ selS,
    const int* __restrict__ selcnt, const int* __restrict__ cl,
    float* __restrict__ ssum, float* __restrict__ scnt)
{
  __shared__ int key[WH];
  __shared__ float vs[WH];
  __shared__ float vc[WH];
  int n = *selcnt;
  for (int i = threadIdx.x; i < WH; i += 256) { key[i] = -1; vs[i] = 0.f; vc[i] = 0.f; }
  __syncthreads();
  int T = gridDim.x*blockDim.x;
  for (int e = blockIdx.x*blockDim.x+threadIdx.x; e < n; e += T) {
    int c = cl[selA[e]];
    float s = selS[e];
    unsigned h = ((unsigned)c * 2654435761u) & (WH-1);
    bool done = false;
    for (int probe = 0; probe < 32; ++probe) {
      int k = key[h];
      if (k == c) { atomicAdd(&vs[h], s); atomicAdd(&vc[h], 1.f); done = true; break; }
      if (k == -1) {
        int old = atomicCAS(&key[h], -1, c);
        if (old == -1 || old == c) { atomicAdd(&vs[h], s); atomicAdd(&vc[h], 1.f); done = true; break; }
      }
      h = (h+1) & (WH-1);
    }
    if (!done) { atomicAdd(&ssum[c], s); atomicAdd(&scnt[c], 1.f); }
  }
  __syncthreads();
  for (int i = threadIdx.x; i < WH; i += 256) {
    if (key[i] >= 0) { atomicAdd(&ssum[key[i]], vs[i]); atomicAdd(&scnt[key[i]], vc[i]); }
  }
}

// p[cluster[v]] += relu(h[v]), run-length flushed per feature lane; 64-node segments
__global__ __launch_bounds__(128) void k_poolsum(const float* __restrict__ h,
                                                 const int* __restrict__ cl, float* __restrict__ p) {
  int f = threadIdx.x;
  int base = blockIdx.x * 64;
  int cur = -1; float acc = 0.f;
  for (int j = 0; j < 64; ++j) {
    int v = base + j;
    if (v >= NN) break;
    int c = cl[v];
    float x = fmaxf(h[(size_t)v*HID + f], 0.f);
    if (c == cur) acc += x;
    else {
      if (cur >= 0) atomicAdd(&p[(size_t)cur*HID + f], acc);
      cur = c; acc = x;
    }
  }
  if (cur >= 0) atomicAdd(&p[(size_t)cur*HID + f], acc);
}

__global__ __launch_bounds__(256) void k_contract(
    const int* __restrict__ eA, const int* __restrict__ eB, const int* cntp, int cnst,
    const int* __restrict__ cl, unsigned long long* __restrict__ tab,
    int* __restrict__ outA, int* __restrict__ outB, int* __restrict__ ocnt, int lev)
{
  int n = edge_count(cntp, cnst);
  int T = gridDim.x*blockDim.x;
  int lane = threadIdx.x & 63;
  for (int e = blockIdx.x*blockDim.x+threadIdx.x; e < n; e += T) {
    int s = eA[e], d = eB[e];
    bool keep = false; int a = 0, b = 0;
    if (s != d) {
      a = cl[s]; b = cl[d];
      if (a != b) {
        unsigned long long key = ((unsigned long long)lev << 34) |
                                 ((unsigned long long)a << 17) | (unsigned long long)b;
        unsigned long long hh = key * 0x9E3779B97F4A7C15ull;
        unsigned idx = (unsigned)(hh >> 40) & (HSZ - 1);
        while (true) {
          unsigned long long prev = atomicCAS(&tab[idx], ~0ull, key);
          if (prev == ~0ull) { keep = true; break; }
          if (prev == key) break;
          idx = (idx + 1) & (HSZ - 1);
        }
      }
    }
    unsigned long long mask = __ballot(keep);
    if (mask) {
      int leader = __ffsll((long long)mask) - 1;
      int total  = __popcll(mask);
      int base = 0;
      if (lane == leader) base = atomicAdd(ocnt, total);
      base = __shfl(base, leader);
      if (keep) {
        int off = __popcll(mask & ((1ull << lane) - 1));
        outA[base+off] = a; outB[base+off] = b;
      }
    }
  }
}

// ---------------- output kernels ----------------

// h1 and u1 are pre-relu -> relu on load; xin raw
__global__ __launch_bounds__(256) void k_matvec384(
    const float* __restrict__ h1, const float* __restrict__ xin,
    const float* __restrict__ u1, const int* __restrict__ cl0,
    const float* __restrict__ Wu2, float* __restrict__ zw)
{
  int l = threadIdx.x & 63;
  int sub = threadIdx.x >> 6;
  float w0 = Wu2[l],     w1 = Wu2[64+l],  w2 = Wu2[128+l];
  float w3 = Wu2[192+l], w4 = Wu2[256+l], w5 = Wu2[320+l];
  for (int g = blockIdx.x; g*4 < NN; g += gridDim.x) {
    int v = g*4 + sub;
    if (v >= NN) continue;
    int gg = cl0[v];
    float s = fmaxf(h1[(size_t)v*HID + l], 0.f)       * w0
            + fmaxf(h1[(size_t)v*HID + 64 + l], 0.f)  * w1
            + xin[(size_t)v*HID + l]                  * w2
            + xin[(size_t)v*HID + 64 + l]             * w3
            + fmaxf(u1[(size_t)gg*HID + l], 0.f)      * w4
            + fmaxf(u1[(size_t)gg*HID + 64 + l], 0.f) * w5;
    #pragma unroll
    for (int off = 32; off; off >>= 1) s += __shfl_down(s, off);
    if (l == 0) zw[v] = s;
  }
}

__global__ void k_final(const float* __restrict__ zw, const int* __restrict__ rp,
                        const int* __restrict__ csr, const float* __restrict__ dinv,
                        const float* __restrict__ bu, float* __restrict__ out) {
  int T = gridDim.x*blockDim.x;
  for (int v = blockIdx.x*blockDim.x+threadIdx.x; v < NN; v += T) {
    float acc = 0.f;
    int p0 = rp[v], p1 = rp[v+1];
    for (int p = p0; p < p1; ++p) { int s = csr[p]; acc += zw[s]*dinv[s]; }
    float dv = dinv[v];
    float t = acc*dv + 2.f*dv*dv*zw[v] + bu[0];
    out[v] = sigmoid_ref(t);
  }
}

// ---------------- host orchestration ----------------

extern "C" void kernel_launch(void* const* d_in, const int* in_sizes, int n_in,
                              void* d_out, int out_size, void* d_ws, size_t ws_size,
                              hipStream_t stream) {
  const float* x_in = (const float*)d_in[0];
  const int*   ei   = (const int*)d_in[1];
  const float* Wd0 = (const float*)d_in[3];  const float* bd0 = (const float*)d_in[4];
  const float* Wd1 = (const float*)d_in[5];  const float* bd1 = (const float*)d_in[6];
  const float* Wd2 = (const float*)d_in[7];  const float* bd2 = (const float*)d_in[8];
  const float* Wd3 = (const float*)d_in[9];  const float* bd3 = (const float*)d_in[10];
  const float* Wp0 = (const float*)d_in[11]; const float* bp0 = (const float*)d_in[12];
  const float* Wp1 = (const float*)d_in[13]; const float* bp1 = (const float*)d_in[14];
  const float* Wp2 = (const float*)d_in[15]; const float* bp2 = (const float*)d_in[16];
  const float* Wu0 = (const float*)d_in[17]; const float* bu0 = (const float*)d_in[18];
  const float* Wu1 = (const float*)d_in[19]; const float* bu1 = (const float*)d_in[20];
  const float* Wu2 = (const float*)d_in[21]; const float* bu2 = (const float*)d_in[22];
  float* out = (float*)d_out;
  (void)in_sizes; (void)n_in; (void)out_size;

  char* wp = (char*)d_ws;
  auto alloc = [&](size_t bytes) -> void* {
    void* p = (void*)wp;
    wp += (bytes + 255) & ~(size_t)255;
    return p;
  };
  float* B[6]; for (int i = 0; i < 6; ++i) B[i] = (float*)alloc((size_t)NN*HID*4);
  int *eA[4], *eB[4];
  for (int i = 0; i < 4; ++i) { eA[i] = (int*)alloc((size_t)EE*4); eB[i] = (int*)alloc((size_t)EE*4); }
  int* cl[3];      for (int i = 0; i < 3; ++i) cl[i]    = (int*)alloc((size_t)NN*4);
  float* dinvL[4]; for (int i = 0; i < 4; ++i) dinvL[i] = (float*)alloc((size_t)NN*4);
  int* rpL[4]; int* csrL[4]; int* dstL[4];
  for (int i = 0; i < 4; ++i) {
    rpL[i]  = (int*)alloc((size_t)(NN+1)*4);
    csrL[i] = (int*)alloc((size_t)EE*4);
    dstL[i] = (int*)alloc((size_t)EE*4);
  }
  int*   selA = (int*)alloc((size_t)EE*4);
  int*   selB = (int*)alloc((size_t)EE*4);
  float* selS = (float*)alloc((size_t)EE*4);
  int* deg    = (int*)alloc((size_t)NN*4);
  int* cursor = (int*)alloc((size_t)NN*4);
  int* bsum   = (int*)alloc(256*4);
  float* an   = (float*)alloc((size_t)NN*4);
  float* bn   = (float*)alloc((size_t)NN*4);
  float* ssum = (float*)alloc((size_t)2*NN*4);
  float* scnt = ssum + NN;
  float* zw   = (float*)alloc((size_t)NN*4);
  int* selcnt = (int*)alloc(256);
  int* ecnt   = (int*)alloc(256);
  int* flags  = (int*)alloc(256);
  unsigned long long* tab = (unsigned long long*)alloc((size_t)HSZ*8);
  if ((size_t)(wp - (char*)d_ws) > ws_size) return;

  k_split_edges<<<1024,256,0,stream>>>(ei, eA[0], eB[0]);
  hipMemsetAsync(tab, 0xFF, (size_t)HSZ*8, stream);

  auto cntp = [&](int lev) -> const int* { return lev ? (ecnt + lev) : nullptr; };

  auto build_level = [&](int lev) {
    hipMemsetAsync(deg, 0, (size_t)NN*4, stream);
    k_degree<<<512,256,0,stream>>>(eB[lev], cntp(lev), EE, deg);
    k_scan1<<<GN,256,0,stream>>>(deg, rpL[lev], bsum);
    k_scan2<<<1,256,0,stream>>>(bsum, rpL[lev], GN);
    k_scan3<<<GN,256,0,stream>>>(rpL[lev], bsum, cursor, deg, dinvL[lev]);
    k_csrfill<<<512,256,0,stream>>>(eA[lev], eB[lev], cntp(lev), EE, cursor, csrL[lev], dstL[lev]);
  };

  const int GAGG = (EE + 8*CH - 1) / (8*CH);
  auto do_conv = [&](const float* A0, int reluA0, const float* rs, const float* rc,
                     const float* A1, const int* i1, int reluA1, int K,
                     const float* W, const float* bias, int lev, float* xs, float* outp) {
    k_matmul<<<(NN+63)/64,256,0,stream>>>(A0, nullptr, reluA0, rs, rc,
                                          A1, i1, reluA1, K, W, dinvL[lev], bias, xs, outp);
    k_edgeagg<<<GAGG,256,0,stream>>>(xs, csrL[lev], dstL[lev], dinvL[lev], outp, cntp(lev), EE);
  };

  auto do_pool = [&](const float* h, int lev, int ci, float* p, const float* Wp, const float* bp) {
    k_node_ab<<<512,256,0,stream>>>(h, Wp, an, bn);
    k_labinit<<<GN,256,0,stream>>>(cl[ci], flags, selcnt, ecnt + lev + 1, ssum);
    k_score_sel<<<512,256,0,stream>>>(eA[lev], eB[lev], cntp(lev), EE, an, bn, bp,
                                      selA, selB, selS, selcnt);
    for (int r = 0; r < CC_ROUNDS; ++r) {
      const int* fp = r ? (flags + r - 1) : nullptr;
      k_ccround<<<512,256,0,stream>>>(selA, selB, selcnt, cl[ci], fp, flags + r);
    }
    k_wsum<<<64,256,0,stream>>>(selA, selS, selcnt, cl[ci], ssum, scnt);
    hipMemsetAsync(p, 0, (size_t)NN*HID*4, stream);
    k_poolsum<<<(NN+63)/64,128,0,stream>>>(h, cl[ci], p);   // raw pooled sums; w applied at next matmul
    k_contract<<<512,256,0,stream>>>(eA[lev], eB[lev], cntp(lev), EE, cl[ci], tab,
                                     eA[lev+1], eB[lev+1], ecnt + lev + 1, lev);
  };

  // ---- down path (h buffers hold PRE-relu values) ----
  build_level(0);
  do_conv(x_in, 0, nullptr, nullptr, nullptr, nullptr, 0, 128, Wd0, bd0, 0, B[5], B[0]); // h1=B0
  do_pool(B[0], 0, 0, B[3], Wp0, bp0);                                                   // p1=B3 (raw)
  build_level(1);
  do_conv(B[3], 0, ssum, scnt, nullptr, nullptr, 0, 128, Wd1, bd1, 1, B[5], B[1]);       // h2=B1
  do_pool(B[1], 1, 1, B[3], Wp1, bp1);                                                   // p2=B3
  build_level(2);
  do_conv(B[3], 0, ssum, scnt, nullptr, nullptr, 0, 128, Wd2, bd2, 2, B[5], B[2]);       // h3=B2
  do_pool(B[2], 2, 2, B[3], Wp2, bp2);                                                   // p3=B3
  build_level(3);
  do_conv(B[3], 0, ssum, scnt, nullptr, nullptr, 0, 128, Wd3, bd3, 3, B[5], B[4]);       // h4=B4 (no relu ever)
  // ---- up path (concat folded; A-relu on load; A1 row-gathered) ----
  do_conv(B[2], 1, nullptr, nullptr, B[4], cl[2], 0, 256, Wu0, bu0, 2, B[5], B[3]);      // u0=B3
  do_conv(B[1], 1, nullptr, nullptr, B[3], cl[1], 1, 256, Wu1, bu1, 1, B[5], B[4]);      // u1=B4
  k_matvec384<<<512,256,0,stream>>>(B[0], x_in, B[4], cl[0], Wu2, zw);
  k_final<<<512,256,0,stream>>>(zw, rpL[0], csrL[0], dinvL[0], bu2, out);
}